// Round 5
// baseline (551.861 us; speedup 1.0000x reference)
//
#include <hip/hip_runtime.h>
#include <stdint.h>

typedef unsigned short u16;
typedef __attribute__((ext_vector_type(8))) _Float16 h8;  // 8 x fp16 (4 VGPRs)
typedef __attribute__((ext_vector_type(2))) __fp16 hp2;   // pkrtz result type
typedef __attribute__((ext_vector_type(4))) float f4;     // 4 x f32 accumulator

#define B_ 2
#define SQ_ 2048
#define SK_ 2048
#define D_ 1024
#define H_ 16
#define DK_ 64

// ---- control block (ints), zeroed by rma_cast_init block 0 each launch ----
#define C_TICKET 0
#define C_CAST   1    // -> 704
#define C_PROJ   2    // -> 512
#define C_RECFIN 4    // -> 8
#define C_RECCU  8    // 8 ints: CU keys of recurrence blocks (|0x10000)
#define C_RDONE  16   // 32 ints: per-128-row projR chunk -> 8 when complete
#define C_PROG   48   // 32 ints: per-bh recurrence progress (t)
#define CTRL_N   128

// ---- ticket pool (dependency order) ----
#define T_PROJR0 0     // 256 projR 128x128 tiles
#define T_CAST0  256   // 704 cast chunks (16384 floats each)
#define T_PQV0   960   // 512 projQ/V tiles
#define T_FLASH0 1472  // 512 flash tasks (128 q rows each)
#define T_END    1984

__device__ __forceinline__ u16 f2h(float f) {             // fp32 -> fp16 RNE
  union { _Float16 h; u16 u; } v; v.h = (_Float16)f; return v.u;
}
__device__ __forceinline__ unsigned pkrtz(float a, float b) {  // v_cvt_pkrtz_f16_f32
  union { hp2 h; unsigned u; } v; v.h = __builtin_amdgcn_cvt_pkrtz(a, b); return v.u;
}
__device__ __forceinline__ float fexp2(float x) {         // raw v_exp_f32 (1 instr)
  float r;
  asm("v_exp_f32 %0, %1" : "=v"(r) : "v"(x));
  return r;
}

typedef const void __attribute__((address_space(1)))* gas1;
typedef void __attribute__((address_space(3)))* las3;
__device__ __forceinline__ void gld16(const void* g, void* l) {
  __builtin_amdgcn_global_load_lds((gas1)g, (las3)l, 16, 0, 0);
}

// relaxed spin; periodic acquire as safety valve (protocol validated in R3).
// R5 hardening: BOUNDED (cap ~16K sleeps ~ 3.5ms) — a broken gate degrades
// into a wrong/slow measurable run instead of a container-killing hang.
__device__ __forceinline__ void spin_ge(int* p, int v) {
  if (__hip_atomic_load(p, __ATOMIC_RELAXED, __HIP_MEMORY_SCOPE_AGENT) >= v) return;
  int n = 0;
  for (;;) {
    __builtin_amdgcn_s_sleep(8);
    int x = ((++n & 63) == 0)
                ? __hip_atomic_load(p, __ATOMIC_ACQUIRE, __HIP_MEMORY_SCOPE_AGENT)
                : __hip_atomic_load(p, __ATOMIC_RELAXED, __HIP_MEMORY_SCOPE_AGENT);
    if (x >= v) return;
    if (n > 16384) return;               // finite-wait safety valve
  }
}

// s_getreg encodings: imm = id | (offset<<6) | ((size-1)<<11)
#define GETREG_HW_ID  (4 | (31 << 11))    // HW_ID, full 32b
#define GETREG_XCC_ID (20 | (31 << 11))   // XCC_ID (gfx940+)

// ---------------------------------------------------------------- cast helper
__device__ __forceinline__ void cast8(const float* __restrict__ src,
                                      u16* __restrict__ dst, int i) {
  float4 a = *(const float4*)(src + i);
  float4 b = *(const float4*)(src + i + 4);
  alignas(16) u16 t[8] = {f2h(a.x), f2h(a.y), f2h(a.z), f2h(a.w),
                          f2h(b.x), f2h(b.y), f2h(b.z), f2h(b.w)};
  *(int4*)(dst + i) = *(int4*)t;
}

// K1: cast R (2048 blocks) + Wr (512 blocks) + zero ctrl (block 0)
__global__ void rma_cast_init(const float* __restrict__ xr, const float* __restrict__ wr,
                              u16* __restrict__ orr, u16* __restrict__ owr,
                              int* __restrict__ ctrl) {
  const int b = blockIdx.x;
  if (b == 0 && threadIdx.x < CTRL_N) ctrl[threadIdx.x] = 0;
  const float* src; u16* dst; int bi;
  if (b < 2048) { src = xr; dst = orr; bi = b; }
  else          { src = wr; dst = owr; bi = b - 2048; }
  cast8(src, dst, (bi * 256 + threadIdx.x) * 8);
}

// ---------------------------------------------------------------- GEMM core 128x128
__device__ __forceinline__ void gemm_mainloop(
    const u16* __restrict__ A, const u16* __restrict__ Bw, int K,
    u16* As, u16* Bs, int m0, int n0, f4 (&acc)[4][4]) {
  const int tid = threadIdx.x;
  const int w = tid >> 6, lane = tid & 63;
  const int quad = lane >> 4, ln = lane & 15;
  const int wm = (w >> 1) * 64, wn = (w & 1) * 64;
  const int c0 = tid, c1 = tid + 256;   // 16B chunk ids; row=c>>2, k8=(c&3)*8
  const u16* a0 = A + (size_t)(m0 + (c0 >> 2)) * K + (c0 & 3) * 8;
  const u16* a1 = A + (size_t)(m0 + (c1 >> 2)) * K + (c1 & 3) * 8;
  const u16* b0 = Bw + (size_t)(n0 + (c0 >> 2)) * K + (c0 & 3) * 8;
  const u16* b1 = Bw + (size_t)(n0 + (c1 >> 2)) * K + (c1 & 3) * 8;
  u16* As0 = As + (0 + w * 64) * 8;     // wave-uniform LDS bases
  u16* As1 = As + (256 + w * 64) * 8;
  u16* Bs0 = Bs + (0 + w * 64) * 8;
  u16* Bs1 = Bs + (256 + w * 64) * 8;
  for (int kt = 0; kt < K; kt += 32) {
    gld16(a0 + kt, As0);
    gld16(a1 + kt, As1);
    gld16(b0 + kt, Bs0);
    gld16(b1 + kt, Bs1);
    __syncthreads();
    h8 af[4], bf[4];
#pragma unroll
    for (int i = 0; i < 4; i++)
      af[i] = *(const h8*)&As[(wm + i * 16 + ln) * 32 + quad * 8];
#pragma unroll
    for (int i = 0; i < 4; i++)
      bf[i] = *(const h8*)&Bs[(wn + i * 16 + ln) * 32 + quad * 8];
#pragma unroll
    for (int i = 0; i < 4; i++)
#pragma unroll
      for (int j = 0; j < 4; j++)
        acc[i][j] = __builtin_amdgcn_mfma_f32_16x16x32_f16(af[i], bf[j], acc[i][j], 0, 0, 0);
    __syncthreads();
  }
}

// ---------------------------------------------------------------- GEMM core 64x128
__device__ __forceinline__ void gemm_mainloop64(
    const u16* __restrict__ A, const u16* __restrict__ Bw, int K,
    u16* As, u16* Bs, int m0, int n0, f4 (&acc)[2][4]) {
  const int tid = threadIdx.x;
  const int w = tid >> 6, lane = tid & 63;
  const int quad = lane >> 4, ln = lane & 15;
  const int wm = (w >> 1) * 32, wn = (w & 1) * 64;
  const u16* a0 = A + (size_t)(m0 + (tid >> 2)) * K + (tid & 3) * 8;
  const u16* b0 = Bw + (size_t)(n0 + (tid >> 2)) * K + (tid & 3) * 8;
  const u16* b1 = Bw + (size_t)(n0 + ((tid + 256) >> 2)) * K + (tid & 3) * 8;
  u16* As0 = As + (w * 64) * 8;
  u16* Bs0 = Bs + (w * 64) * 8;
  u16* Bs1 = Bs + (256 + w * 64) * 8;
  for (int kt = 0; kt < K; kt += 32) {
    gld16(a0 + kt, As0);
    gld16(b0 + kt, Bs0);
    gld16(b1 + kt, Bs1);
    __syncthreads();
    h8 af[2], bf[4];
#pragma unroll
    for (int i = 0; i < 2; i++)
      af[i] = *(const h8*)&As[(wm + i * 16 + ln) * 32 + quad * 8];
#pragma unroll
    for (int j = 0; j < 4; j++)
      bf[j] = *(const h8*)&Bs[(wn + j * 16 + ln) * 32 + quad * 8];
#pragma unroll
    for (int i = 0; i < 2; i++)
#pragma unroll
      for (int j = 0; j < 4; j++)
        acc[i][j] = __builtin_amdgcn_mfma_f32_16x16x32_f16(af[i], bf[j], acc[i][j], 0, 0, 0);
    __syncthreads();
  }
}

// ---------------------------------------------------------------- recurrence
// h_t = tanh(h_{t-1}*ws + r_t), exact scan in exp-domain (4-op chain:
// add -> rcp -> fma -> exp2).  Blocks 0..7, one bh per wave, gated on projR
// chunk counters; publishes per-bh progress every 128 t.  (protocol: R3)
#define RB_ 32
__device__ void recur_run(const float* __restrict__ Rp, const float* __restrict__ Wh,
                          u16* __restrict__ Hst, int* ctrl) {
  __builtin_amdgcn_s_setprio(2);
  const int tid = threadIdx.x;
  const int ch = blockIdx.x * 256 + tid;     // 0..2047
  const int bh = ch >> 6, d = ch & 63, h = bh & 15, b = bh >> 4;
  const float* wr = Wh + (h * 64 + d) * 64;
  float ws = 0.f;
#pragma unroll
  for (int k = 0; k < 64; k += 4) {
    float4 wv4 = *(const float4*)(wr + k);
    ws += (wv4.x + wv4.y) + (wv4.z + wv4.w);
  }
  const float C2 = 2.885390081777927f;   // 2*log2(e)
  const float wsC2 = ws * C2;
  const float Kw = 2.0f * wsC2;
  const size_t base = (size_t)bh * (SK_ * DK_) + d;
  const float* r = Rp + base;
  u16* o = Hst + base;
  int* rd = ctrl + C_RDONE + b * 16;     // 16 chunks of 128 rows for this b
  int* pg = ctrl + C_PROG + bh;
  spin_ge(&rd[0], 8);                    // rows [0,128) of our b ready
  float cur[RB_], nxt[RB_];
#pragma unroll
  for (int j = 0; j < RB_; j++) cur[j] = r[(size_t)j * DK_];
  float e = fexp2(cur[0] * C2);          // e_0 (h_{-1} = 0)
  for (int t0 = 0; t0 < SK_; t0 += RB_) {
    const int t1 = t0 + RB_;
    if (t1 < SK_ && ((t1 & 127) == 0)) spin_ge(&rd[t1 >> 7], 8);
    const int tn = (t1 < SK_) ? t1 : t0;  // dummy reload at end
#pragma unroll
    for (int j = 0; j < RB_; j++) nxt[j] = r[(size_t)(tn + j) * DK_];
#pragma unroll
    for (int j = 0; j < RB_; j++) {
      const float a = e + 1.0f;                          // chain 1
      const float bb = __builtin_amdgcn_rcpf(a);         // chain 2
      const float hs = __builtin_fmaf(-2.0f, bb, 1.0f);  // off-chain output
      o[(size_t)(t0 + j) * DK_] = f2h(hs);
      const float rn = (j + 1 < RB_) ? cur[j + 1] : nxt[0];
      const float K = __builtin_fmaf(C2, rn, wsC2);      // off-chain
      const float x = __builtin_fmaf(-Kw, bb, K);        // chain 3
      e = fexp2(x);                                      // chain 4
    }
    if (((t1 & 127) == 0) && (tid & 63) == 0)
      __hip_atomic_store(pg, t1, __ATOMIC_RELEASE, __HIP_MEMORY_SCOPE_AGENT);
#pragma unroll
    for (int j = 0; j < RB_; j++) cur[j] = nxt[j];
  }
  __builtin_amdgcn_s_setprio(0);
}

// ---------------------------------------------------------------- flash task
// 128 q rows, 4 waves; identical to the proven R2 kernel plus per-K-tile
// progress gating folded into the existing loop-top barrier.
#define FXM_ 12.0f
__device__ void flash_task(int fidx, const u16* __restrict__ Qb,
                           const u16* __restrict__ Hst, const u16* __restrict__ Vt,
                           u16* __restrict__ Og, u16* smem, int* ctrl) {
  const int tid = threadIdx.x;
  const int w = tid >> 6, lane = tid & 63;
  const int quad = lane >> 4, ln = lane & 15;
  const int bh = fidx >> 4, qtile = fidx & 15;
  const int q0 = qtile * 128 + w * 32;
  u16* Kt = smem;                      // [64][72]
  u16* Vts = smem + 64 * 72;           // [64][72]
  u16* Pw = smem + 2 * 64 * 72 + w * (32 * 72);
  const float scale2 = 0.18033688011112042f;  // log2(e)/sqrt(DK)
  const u16* Qg = Qb + (size_t)bh * SQ_ * DK_;
  const u16* Kg = Hst + (size_t)bh * SK_ * DK_;
  const u16* Vg = Vt + (size_t)bh * DK_ * SK_;
  int* pg = ctrl + C_PROG + bh;
  if (tid == 0) { spin_ge(&ctrl[C_PROJ], 512); spin_ge(pg, 64); }
  __syncthreads();
  h8 qf[2][2];
#pragma unroll
  for (int qt = 0; qt < 2; qt++)
#pragma unroll
    for (int c = 0; c < 2; c++)
      qf[qt][c] = *(const h8*)&Qg[(size_t)(q0 + qt * 16 + ln) * DK_ + c * 32 + quad * 8];
  f4 o[4][2] = {};                 // O^T[d=dt*16+quad*4+r][q=qt*16+ln]
  float l[2] = {0.f, 0.f};
  // staging map: 512 chunks of 16B; thread stages c0=tid and c1=tid+256
  const int c0 = tid, c1 = tid + 256;
  const int r0 = c0 >> 3, o0 = (c0 & 7) * 8;
  const int r1 = c1 >> 3, o1 = (c1 & 7) * 8;
  const u16* kg0 = Kg + (size_t)r0 * DK_ + o0;
  const u16* kg1 = Kg + (size_t)r1 * DK_ + o1;
  const u16* vg0 = Vg + (size_t)r0 * SK_ + o0;
  const u16* vg1 = Vg + (size_t)r1 * SK_ + o1;
  u16* kl0 = &Kt[r0 * 72 + o0];
  u16* kl1 = &Kt[r1 * 72 + o1];
  u16* vl0 = &Vts[r0 * 72 + o0];
  u16* vl1 = &Vts[r1 * 72 + o1];
  // prologue: tile kt=0 (rows [0,64) released above)
  int4 ks0 = *(const int4*)(kg0);
  int4 ks1 = *(const int4*)(kg1);
  int4 vs0 = *(const int4*)(vg0);
  int4 vs1 = *(const int4*)(vg1);
  int seen = 64;
  for (int kt = 0; kt < SK_; kt += 64) {
    if (tid == 0) {   // gate THIS iteration's prefetch (rows [kt+64,kt+128))
      const int need = (kt + 128 <= SK_) ? kt + 128 : SK_;
      if (seen < need) { spin_ge(pg, need); seen = need; }
    }
    __syncthreads();               // gate + prior tile's fragment reads done
    *(int4*)kl0 = ks0;
    *(int4*)kl1 = ks1;
    *(int4*)vl0 = vs0;
    *(int4*)vl1 = vs1;
    __syncthreads();               // tile staged
    h8 kf[4][2], vf[4][2];
#pragma unroll
    for (int m = 0; m < 4; m++) {
      kf[m][0] = *(const h8*)&Kt[(m * 16 + ln) * 72 + quad * 8];
      kf[m][1] = *(const h8*)&Kt[(m * 16 + ln) * 72 + 32 + quad * 8];
    }
#pragma unroll
    for (int dt = 0; dt < 4; dt++) {
      vf[dt][0] = *(const h8*)&Vts[(dt * 16 + ln) * 72 + quad * 8];
      vf[dt][1] = *(const h8*)&Vts[(dt * 16 + ln) * 72 + 32 + quad * 8];
    }
    const int ktn = (kt + 64 < SK_) ? kt + 64 : 0;
    ks0 = *(const int4*)(kg0 + (size_t)ktn * DK_);
    ks1 = *(const int4*)(kg1 + (size_t)ktn * DK_);
    vs0 = *(const int4*)(vg0 + ktn);
    vs1 = *(const int4*)(vg1 + ktn);
    f4 st[4][2];
#pragma unroll
    for (int m = 0; m < 4; m++)
#pragma unroll
      for (int qt = 0; qt < 2; qt++) {
        f4 t = {0.f, 0.f, 0.f, 0.f};
        t = __builtin_amdgcn_mfma_f32_16x16x32_f16(kf[m][0], qf[qt][0], t, 0, 0, 0);
        t = __builtin_amdgcn_mfma_f32_16x16x32_f16(kf[m][1], qf[qt][1], t, 0, 0, 0);
        st[m][qt] = t;
      }
#pragma unroll
    for (int qt = 0; qt < 2; qt++)
#pragma unroll
      for (int m = 0; m < 4; m++) {
        const float p0 = fexp2(__builtin_fmaf(st[m][qt][0], scale2, -FXM_));
        const float p1 = fexp2(__builtin_fmaf(st[m][qt][1], scale2, -FXM_));
        const float p2 = fexp2(__builtin_fmaf(st[m][qt][2], scale2, -FXM_));
        const float p3 = fexp2(__builtin_fmaf(st[m][qt][3], scale2, -FXM_));
        l[qt] += (p0 + p1) + (p2 + p3);
        uint2 pk;
        pk.x = pkrtz(p0, p1);
        pk.y = pkrtz(p2, p3);
        *(uint2*)&Pw[(qt * 16 + ln) * 72 + m * 16 + quad * 4] = pk;
      }
    asm volatile("" ::: "memory");   // wave-private LDS write->read ordering
#pragma unroll
    for (int c = 0; c < 2; c++) {
      h8 pb0 = *(const h8*)&Pw[(0 + ln) * 72 + c * 32 + quad * 8];
      h8 pb1 = *(const h8*)&Pw[(16 + ln) * 72 + c * 32 + quad * 8];
#pragma unroll
      for (int dt = 0; dt < 4; dt++) {
        o[dt][0] = __builtin_amdgcn_mfma_f32_16x16x32_f16(vf[dt][c], pb0, o[dt][0], 0, 0, 0);
        o[dt][1] = __builtin_amdgcn_mfma_f32_16x16x32_f16(vf[dt][c], pb1, o[dt][1], 0, 0, 0);
      }
    }
  }
  const int b = bh >> 4, h = bh & 15;
#pragma unroll
  for (int qt = 0; qt < 2; qt++) {
    float lq = l[qt];
    lq += __shfl_xor(lq, 16);
    lq += __shfl_xor(lq, 32);
    const float linv = __builtin_amdgcn_rcpf(lq);
    const int q = q0 + qt * 16 + ln;
#pragma unroll
    for (int dt = 0; dt < 4; dt++) {
      uint2 pk;
      pk.x = pkrtz(o[dt][qt][0] * linv, o[dt][qt][1] * linv);
      pk.y = pkrtz(o[dt][qt][2] * linv, o[dt][qt][3] * linv);
      *(uint2*)&Og[((size_t)b * SQ_ + q) * D_ + h * DK_ + dt * 16 + quad * 4] = pk;
    }
  }
  __syncthreads();     // all waves done with smem before next ticket reuses it
}

// ---------------------------------------------------------------- mega kernel
// 520 blocks x 256 thr, 56KB static LDS -> exactly 2 blocks/CU.
// Blocks 0..7: recurrence (publish physical CU key; the CU-partner worker
// parks, bounded, until C_RECFIN==8).  All other blocks: ticket pool.
__global__ __launch_bounds__(256, 2)
void rma_mega(const float* __restrict__ query, const float* __restrict__ value,
              const float* __restrict__ Wq, const float* __restrict__ Wv,
              const float* __restrict__ Wo, u16* __restrict__ Xq,
              u16* __restrict__ Xv, u16* __restrict__ Wqb, u16* __restrict__ Wvb,
              u16* __restrict__ Wob, const u16* __restrict__ Xr,
              const u16* __restrict__ Wrb, const float* __restrict__ br,
              float* __restrict__ Rp, const float* __restrict__ Wh,
              u16* __restrict__ Hst, const float* __restrict__ bq,
              const float* __restrict__ bv, u16* __restrict__ Qb,
              u16* __restrict__ Vt, u16* __restrict__ Og,
              int* __restrict__ ctrl) {
  __shared__ __align__(16) u16 smem[28672];   // 57344B: 2 blocks/CU exactly
  __shared__ int s_t, s_mycu;
  const int tid = threadIdx.x;
  const bool is_recur = blockIdx.x < 8;
  if (tid == 0) {
    const int hwid = __builtin_amdgcn_s_getreg(GETREG_HW_ID);
    const int xcc = __builtin_amdgcn_s_getreg(GETREG_XCC_ID);
    s_mycu = (((xcc & 15) << 8) | ((hwid >> 8) & 0xFF)) | 0x10000;
    if (is_recur)
      __hip_atomic_store(&ctrl[C_RECCU + blockIdx.x], s_mycu, __ATOMIC_RELAXED,
                         __HIP_MEMORY_SCOPE_AGENT);
  }
  __syncthreads();
  const int mycu = s_mycu;
  if (is_recur) {
    recur_run(Rp, Wh, Hst, ctrl);
    if (tid == 0)
      __hip_atomic_fetch_add(&ctrl[C_RECFIN], 1, __ATOMIC_RELEASE,
                             __HIP_MEMORY_SCOPE_AGENT);
    // fall through: this CU is free now, join the worker pool
  }
  u16* As = smem;
  u16* Bs = smem + 4096;
  int park_budget = 300;   // x ~0.43us -> cap ~130us: deadlock-proof
  for (;;) {
    if (tid == 0) {
      if (!is_recur &&
          __hip_atomic_load(&ctrl[C_RECFIN], __ATOMIC_RELAXED,
                            __HIP_MEMORY_SCOPE_AGENT) < 8) {
        bool hosted = false;
#pragma unroll
        for (int i = 0; i < 8; i++)
          if (__hip_atomic_load(&ctrl[C_RECCU + i], __ATOMIC_RELAXED,
                                __HIP_MEMORY_SCOPE_AGENT) == mycu)
            hosted = true;
        if (hosted) {   // park (bounded): leave the CU to the recurrence chain
          while (park_budget > 0 &&
                 __hip_atomic_load(&ctrl[C_RECFIN], __ATOMIC_RELAXED,
                                   __HIP_MEMORY_SCOPE_AGENT) < 8) {
            __builtin_amdgcn_s_sleep(16);
            park_budget--;
          }
        }
      }
      s_t = atomicAdd(&ctrl[C_TICKET], 1);
    }
    __syncthreads();
    const int t = s_t;
    if (t >= T_END) return;
    if (t < T_CAST0) {
      // ---------------- projR tile (m 0..31, n 0..7)
      const int idx = t - T_PROJR0;
      const int m = idx & 31, n0 = (idx >> 5) << 7, m0 = m << 7;
      f4 acc[4][4] = {};
      gemm_mainloop(Xr, Wrb, D_, As, Bs, m0, n0, acc);
      const int w = tid >> 6, lane = tid & 63;
      const int quad = lane >> 4, ln = lane & 15;
      const int wm = (w >> 1) * 64, wn = (w & 1) * 64;
#pragma unroll
      for (int i = 0; i < 4; i++)
#pragma unroll
        for (int j = 0; j < 4; j++) {
          const int colg = n0 + wn + j * 16 + ln;
          const float bb = br[colg];
          const int h = colg >> 6, d = colg & 63;
          const int row4 = m0 + wm + i * 16 + quad * 4;
          const int b = row4 >> 11, s = row4 & 2047;
#pragma unroll
          for (int r = 0; r < 4; r++)
            Rp[((size_t)(b * H_ + h) * SK_ + (s + r)) * DK_ + d] = acc[i][j][r] + bb;
        }
      __syncthreads();                        // all waves' stores drained
      if (tid == 0)
        __hip_atomic_fetch_add(&ctrl[C_RDONE + m], 1, __ATOMIC_RELEASE,
                               __HIP_MEMORY_SCOPE_AGENT);
    } else if (t < T_PQV0) {
      // ---------------- cast chunk (16384 floats)
      const int ci = t - T_CAST0;
      const float* src; u16* dst; int off;
      if (ci < 256)      { src = query; dst = Xq;  off = ci << 14; }
      else if (ci < 512) { src = value; dst = Xv;  off = (ci - 256) << 14; }
      else if (ci < 576) { src = Wq;    dst = Wqb; off = (ci - 512) << 14; }
      else if (ci < 640) { src = Wv;    dst = Wvb; off = (ci - 576) << 14; }
      else               { src = Wo;    dst = Wob; off = (ci - 640) << 14; }
#pragma unroll
      for (int it = 0; it < 8; it++) cast8(src, dst, off + it * 2048 + tid * 8);
      __syncthreads();
      if (tid == 0)
        __hip_atomic_fetch_add(&ctrl[C_CAST], 1, __ATOMIC_RELEASE,
                               __HIP_MEMORY_SCOPE_AGENT);
    } else if (t < T_FLASH0) {
      // ---------------- projQ/V tile
      const int idx = t - T_PQV0;
      const int z = idx >> 8, t2 = idx & 255;
      const int m0 = (t2 & 31) << 7, n0 = (t2 >> 5) << 7;
      if (tid == 0) spin_ge(&ctrl[C_CAST], 704);
      __syncthreads();
      const u16* A = z == 0 ? Xq : Xv;
      const u16* Bw = z == 0 ? Wqb : Wvb;
      const float* bias = z == 0 ? bq : bv;
      f4 acc[4][4] = {};
      gemm_mainloop(A, Bw, D_, As, Bs, m0, n0, acc);
      const int w = tid >> 6, lane = tid & 63;
      const int quad = lane >> 4, ln = lane & 15;
      const int wm = (w >> 1) * 64, wn = (w & 1) * 64;
#pragma unroll
      for (int i = 0; i < 4; i++)
#pragma unroll
        for (int j = 0; j < 4; j++) {
          const int colg = n0 + wn + j * 16 + ln;
          const float bb = bias[colg];
          const int h = colg >> 6, d = colg & 63;
          const int row4 = m0 + wm + i * 16 + quad * 4;
          const int b = row4 >> 11, s = row4 & 2047;
          if (z == 1) {
            uint2 pk;
            pk.x = pkrtz(acc[i][j][0] + bb, acc[i][j][1] + bb);
            pk.y = pkrtz(acc[i][j][2] + bb, acc[i][j][3] + bb);
            *(uint2*)&Vt[((size_t)((b * H_ + h) * DK_ + d)) * SK_ + s] = pk;
          } else {
#pragma unroll
            for (int r = 0; r < 4; r++)
              Qb[((size_t)(b * H_ + h) * SK_ + (s + r)) * DK_ + d] =
                  f2h(acc[i][j][r] + bb);
          }
        }
      __syncthreads();
      if (tid == 0)
        __hip_atomic_fetch_add(&ctrl[C_PROJ], 1, __ATOMIC_RELEASE,
                               __HIP_MEMORY_SCOPE_AGENT);
    } else {
      // ---------------- flash task (gated internally, all waits bounded)
      flash_task(t - T_FLASH0, Qb, Hst, Vt, Og, smem, ctrl);
    }
  }
}

__global__ __launch_bounds__(256, 2)
void rma_final_gemm(const u16* __restrict__ Og, const u16* __restrict__ Wo,
                    const float* __restrict__ bo, float* __restrict__ out) {
  __shared__ u16 As[64 * 32];
  __shared__ u16 Bs[128 * 32];
  const int m0 = blockIdx.x * 64, n0 = blockIdx.y * 128;
  f4 acc[2][4] = {};
  gemm_mainloop64(Og, Wo, D_, As, Bs, m0, n0, acc);
  const int tid = threadIdx.x;
  const int w = tid >> 6, lane = tid & 63;
  const int quad = lane >> 4, ln = lane & 15;
  const int wm = (w >> 1) * 32, wn = (w & 1) * 64;
#pragma unroll
  for (int i = 0; i < 2; i++)
#pragma unroll
    for (int j = 0; j < 4; j++) {
      const int colg = n0 + wn + j * 16 + ln;
      const float bb = bo[colg];
#pragma unroll
      for (int r = 0; r < 4; r++) {
        const int rowg = m0 + wm + i * 16 + quad * 4 + r;
        out[(size_t)rowg * D_ + colg] = acc[i][j][r] + bb;
      }
    }
}

// ---------------------------------------------------------------- launch
extern "C" void kernel_launch(void* const* d_in, const int* in_sizes, int n_in,
                              void* d_out, int out_size, void* d_ws, size_t ws_size,
                              hipStream_t stream) {
  const float* query = (const float*)d_in[0];
  // d_in[1] = key : unused by the reference forward
  const float* value = (const float*)d_in[2];
  const float* R = (const float*)d_in[3];
  const float* Wq = (const float*)d_in[4];
  const float* bq = (const float*)d_in[5];
  const float* Wv = (const float*)d_in[6];
  const float* bv = (const float*)d_in[7];
  const float* Wr = (const float*)d_in[8];
  const float* br = (const float*)d_in[9];
  const float* W_h = (const float*)d_in[10];
  const float* Wo = (const float*)d_in[11];
  const float* bo = (const float*)d_in[12];
  float* out = (float*)d_out;

  char* ws = (char*)d_ws;
  const size_t MB = 1 << 20;
  u16* Xq = (u16*)(ws + 0 * MB);      // 8MB fp16 query
  u16* Xv = (u16*)(ws + 8 * MB);      // 8MB fp16 value
  u16* Xr = (u16*)(ws + 16 * MB);     // 8MB fp16 R
  u16* Wqb = (u16*)(ws + 24 * MB);    // 2MB
  u16* Wvb = (u16*)(ws + 26 * MB);    // 2MB
  u16* Wrb = (u16*)(ws + 28 * MB);    // 2MB
  u16* Wob = (u16*)(ws + 30 * MB);    // 2MB
  u16* Qb = (u16*)(ws + 32 * MB);     // 8MB fp16 (B,H,SQ,DK)
  u16* Vt = (u16*)(ws + 40 * MB);     // 8MB fp16 (B,H,DK,SK)
  float* Rp = (float*)(ws + 48 * MB); // 16MB f32 (B,H,SK,DK)
  u16* Hs = (u16*)(ws + 64 * MB);     // 8MB fp16 (B,H,SK,DK)
  u16* Og = (u16*)(ws + 72 * MB);     // 8MB fp16 (B,SQ,D)
  int* ctrl = (int*)(ws + 80 * MB);   // control block (zeroed by K1)

  rma_cast_init<<<dim3(2560), 256, 0, stream>>>(R, Wr, Xr, Wrb, ctrl);
  rma_mega<<<dim3(520), 256, 0, stream>>>(query, value, Wq, Wv, Wo, Xq, Xv, Wqb,
                                          Wvb, Wob, Xr, Wrb, br, Rp, W_h, Hs, bq,
                                          bv, Qb, Vt, Og, ctrl);
  rma_final_gemm<<<dim3(64, 8), 256, 0, stream>>>(Og, Wob, bo, out);
}

// Round 6
// 286.050 us; speedup vs baseline: 1.9292x; 1.9292x over previous
//
#include <hip/hip_runtime.h>
#include <stdint.h>

typedef unsigned short u16;
typedef __attribute__((ext_vector_type(8))) _Float16 h8;  // 8 x fp16 (4 VGPRs)
typedef __attribute__((ext_vector_type(2))) __fp16 hp2;   // pkrtz result type
typedef __attribute__((ext_vector_type(4))) float f4;     // 4 x f32 accumulator

#define B_ 2
#define SQ_ 2048
#define SK_ 2048
#define D_ 1024
#define H_ 16
#define DK_ 64

// ctrl: 32 per-bh recurrence progress counters, spread 16 ints (64B) apart
// to avoid cacheline ping-pong between 32 writers and ~500 pollers.
#define C_PROG  0
#define CTRL_N  512

__device__ __forceinline__ u16 f2h(float f) {             // fp32 -> fp16 RNE
  union { _Float16 h; u16 u; } v; v.h = (_Float16)f; return v.u;
}
__device__ __forceinline__ unsigned pkrtz(float a, float b) {  // v_cvt_pkrtz_f16_f32
  union { hp2 h; unsigned u; } v; v.h = __builtin_amdgcn_cvt_pkrtz(a, b); return v.u;
}
__device__ __forceinline__ float fexp2(float x) {         // raw v_exp_f32 (1 instr)
  float r;
  asm("v_exp_f32 %0, %1" : "=v"(r) : "v"(x));
  return r;
}

typedef const void __attribute__((address_space(1)))* gas1;
typedef void __attribute__((address_space(3)))* las3;
__device__ __forceinline__ void gld16(const void* g, void* l) {
  __builtin_amdgcn_global_load_lds((gas1)g, (las3)l, 16, 0, 0);
}

// relaxed spin, periodic acquire, BOUNDED (protocol validated R3/R5).
__device__ __forceinline__ void spin_ge(int* p, int v) {
  if (__hip_atomic_load(p, __ATOMIC_RELAXED, __HIP_MEMORY_SCOPE_AGENT) >= v) return;
  int n = 0;
  for (;;) {
    __builtin_amdgcn_s_sleep(16);
    int x = ((++n & 63) == 0)
                ? __hip_atomic_load(p, __ATOMIC_ACQUIRE, __HIP_MEMORY_SCOPE_AGENT)
                : __hip_atomic_load(p, __ATOMIC_RELAXED, __HIP_MEMORY_SCOPE_AGENT);
    if (x >= v) return;
    if (n > 8192) return;               // finite-wait safety valve (~3.5ms)
  }
}

// ---------------------------------------------------------------- cast helper
__device__ __forceinline__ void cast8(const float* __restrict__ src,
                                      u16* __restrict__ dst, int i) {
  float4 a = *(const float4*)(src + i);
  float4 b = *(const float4*)(src + i + 4);
  alignas(16) u16 t[8] = {f2h(a.x), f2h(a.y), f2h(a.z), f2h(a.w),
                          f2h(b.x), f2h(b.y), f2h(b.z), f2h(b.w)};
  *(int4*)(dst + i) = *(int4*)t;
}

// K1: cast ALL fp32 inputs to fp16 + zero ctrl (block 0)
__global__ void rma_cast_all(const float* __restrict__ xq, const float* __restrict__ xv,
                             const float* __restrict__ xr, const float* __restrict__ wq,
                             const float* __restrict__ wv, const float* __restrict__ wr,
                             const float* __restrict__ wo, u16* __restrict__ oxq,
                             u16* __restrict__ oxv, u16* __restrict__ oxr,
                             u16* __restrict__ owq, u16* __restrict__ owv,
                             u16* __restrict__ owr, u16* __restrict__ owo,
                             int* __restrict__ ctrl) {
  const int b = blockIdx.x;
  if (b == 0) { ctrl[threadIdx.x] = 0; ctrl[256 + threadIdx.x] = 0; }
  const float* src; u16* dst; int bi;
  if (b < 2048)      { src = xq; dst = oxq; bi = b; }
  else if (b < 4096) { src = xv; dst = oxv; bi = b - 2048; }
  else if (b < 6144) { src = xr; dst = oxr; bi = b - 4096; }
  else if (b < 6656) { src = wq; dst = owq; bi = b - 6144; }
  else if (b < 7168) { src = wv; dst = owv; bi = b - 6656; }
  else if (b < 7680) { src = wr; dst = owr; bi = b - 7168; }
  else               { src = wo; dst = owo; bi = b - 7680; }
  cast8(src, dst, (bi * 256 + threadIdx.x) * 8);
}

// ---------------------------------------------------------------- GEMM core 128x128
__device__ __forceinline__ void gemm_mainloop(
    const u16* __restrict__ A, const u16* __restrict__ Bw, int K,
    u16* As, u16* Bs, int m0, int n0, f4 (&acc)[4][4]) {
  const int tid = threadIdx.x;
  const int w = tid >> 6, lane = tid & 63;
  const int quad = lane >> 4, ln = lane & 15;
  const int wm = (w >> 1) * 64, wn = (w & 1) * 64;
  const int c0 = tid, c1 = tid + 256;   // 16B chunk ids; row=c>>2, k8=(c&3)*8
  const u16* a0 = A + (size_t)(m0 + (c0 >> 2)) * K + (c0 & 3) * 8;
  const u16* a1 = A + (size_t)(m0 + (c1 >> 2)) * K + (c1 & 3) * 8;
  const u16* b0 = Bw + (size_t)(n0 + (c0 >> 2)) * K + (c0 & 3) * 8;
  const u16* b1 = Bw + (size_t)(n0 + (c1 >> 2)) * K + (c1 & 3) * 8;
  u16* As0 = As + (0 + w * 64) * 8;     // wave-uniform LDS bases
  u16* As1 = As + (256 + w * 64) * 8;
  u16* Bs0 = Bs + (0 + w * 64) * 8;
  u16* Bs1 = Bs + (256 + w * 64) * 8;
  for (int kt = 0; kt < K; kt += 32) {
    gld16(a0 + kt, As0);
    gld16(a1 + kt, As1);
    gld16(b0 + kt, Bs0);
    gld16(b1 + kt, Bs1);
    __syncthreads();
    h8 af[4], bf[4];
#pragma unroll
    for (int i = 0; i < 4; i++)
      af[i] = *(const h8*)&As[(wm + i * 16 + ln) * 32 + quad * 8];
#pragma unroll
    for (int i = 0; i < 4; i++)
      bf[i] = *(const h8*)&Bs[(wn + i * 16 + ln) * 32 + quad * 8];
#pragma unroll
    for (int i = 0; i < 4; i++)
#pragma unroll
      for (int j = 0; j < 4; j++)
        acc[i][j] = __builtin_amdgcn_mfma_f32_16x16x32_f16(af[i], bf[j], acc[i][j], 0, 0, 0);
    __syncthreads();
  }
}

// ---------------------------------------------------------------- GEMM core 64x128
__device__ __forceinline__ void gemm_mainloop64(
    const u16* __restrict__ A, const u16* __restrict__ Bw, int K,
    u16* As, u16* Bs, int m0, int n0, f4 (&acc)[2][4]) {
  const int tid = threadIdx.x;
  const int w = tid >> 6, lane = tid & 63;
  const int quad = lane >> 4, ln = lane & 15;
  const int wm = (w >> 1) * 32, wn = (w & 1) * 64;
  const u16* a0 = A + (size_t)(m0 + (tid >> 2)) * K + (tid & 3) * 8;
  const u16* b0 = Bw + (size_t)(n0 + (tid >> 2)) * K + (tid & 3) * 8;
  const u16* b1 = Bw + (size_t)(n0 + ((tid + 256) >> 2)) * K + (tid & 3) * 8;
  u16* As0 = As + (w * 64) * 8;
  u16* Bs0 = Bs + (w * 64) * 8;
  u16* Bs1 = Bs + (256 + w * 64) * 8;
  for (int kt = 0; kt < K; kt += 32) {
    gld16(a0 + kt, As0);
    gld16(b0 + kt, Bs0);
    gld16(b1 + kt, Bs1);
    __syncthreads();
    h8 af[2], bf[4];
#pragma unroll
    for (int i = 0; i < 2; i++)
      af[i] = *(const h8*)&As[(wm + i * 16 + ln) * 32 + quad * 8];
#pragma unroll
    for (int j = 0; j < 4; j++)
      bf[j] = *(const h8*)&Bs[(wn + j * 16 + ln) * 32 + quad * 8];
#pragma unroll
    for (int i = 0; i < 2; i++)
#pragma unroll
      for (int j = 0; j < 4; j++)
        acc[i][j] = __builtin_amdgcn_mfma_f32_16x16x32_f16(af[i], bf[j], acc[i][j], 0, 0, 0);
    __syncthreads();
  }
}

// K2: all three projections (z: 0=Q fp16, 1=V^T fp16, 2=R f32) — proven R1/R2 code
__global__ __launch_bounds__(256, 2)
void rma_proj_gemm(const u16* __restrict__ Xq, const u16* __restrict__ Xv,
                   const u16* __restrict__ Xr, const u16* __restrict__ Wq,
                   const u16* __restrict__ Wv, const u16* __restrict__ Wr,
                   const float* __restrict__ bq, const float* __restrict__ bv,
                   const float* __restrict__ br, u16* __restrict__ Qb,
                   u16* __restrict__ Vt, float* __restrict__ Rp) {
  const int z = blockIdx.z;
  const u16* A = z == 0 ? Xq : (z == 1 ? Xv : Xr);
  const u16* Bw = z == 0 ? Wq : (z == 1 ? Wv : Wr);
  const float* bias = z == 0 ? bq : (z == 1 ? bv : br);
  __shared__ u16 As[128 * 32];
  __shared__ u16 Bs[128 * 32];
  const int m0 = blockIdx.x * 128, n0 = blockIdx.y * 128;
  f4 acc[4][4] = {};
  gemm_mainloop(A, Bw, D_, As, Bs, m0, n0, acc);
  const int tid = threadIdx.x;
  const int w = tid >> 6, lane = tid & 63;
  const int quad = lane >> 4, ln = lane & 15;
  const int wm = (w >> 1) * 64, wn = (w & 1) * 64;
#pragma unroll
  for (int i = 0; i < 4; i++)
#pragma unroll
    for (int j = 0; j < 4; j++) {
      const int colg = n0 + wn + j * 16 + ln;
      const float bb = bias[colg];
      const int h = colg >> 6, d = colg & 63;
      const int row4 = m0 + wm + i * 16 + quad * 4;  // 4 consecutive rows
      const int b = row4 >> 11, s = row4 & 2047;
      if (z == 1) {
        // V^T: (bh, d, s) — 4 consecutive s, packed 8B store
        uint2 pk;
        pk.x = pkrtz(acc[i][j][0] + bb, acc[i][j][1] + bb);
        pk.y = pkrtz(acc[i][j][2] + bb, acc[i][j][3] + bb);
        *(uint2*)&Vt[((size_t)((b * H_ + h) * DK_ + d)) * SK_ + s] = pk;
      } else {
#pragma unroll
        for (int r = 0; r < 4; r++) {
          const float v = acc[i][j][r] + bb;
          const size_t idx = ((size_t)(b * H_ + h) * SK_ + (s + r)) * DK_ + d;
          if (z == 2) Rp[idx] = v;
          else Qb[idx] = f2h(v);
        }
      }
    }
}

// ---------------------------------------------------------------- K3: recur + flash
// Blocks 0..7: recurrence — h_t = tanh(h_{t-1}*ws + r_t), exact scan in the
// exp-domain (4-op chain add->rcp->fma->exp2); publishes per-bh progress
// every 128 t (release, 64B-spread counters).
// Blocks 8..519: flash tasks (bh, 128 q rows), per-K-tile gated on the bh's
// progress counter via bounded s_sleep spins.  Trailing flash blocks are
// ~70% asleep (release cadence ~2us vs 0.6us compute), so chain interference
// on the 8 shared CUs is mild — unlike the R1/R3 GEMM co-residency failures.
#define RB_ 32
__device__ void recur_run(const float* __restrict__ Rp, const float* __restrict__ Wh,
                          u16* __restrict__ Hst, int* ctrl) {
  __builtin_amdgcn_s_setprio(2);
  const int tid = threadIdx.x;
  const int ch = blockIdx.x * 256 + tid;     // 0..2047
  const int bh = ch >> 6, d = ch & 63, h = bh & 15;
  const float* wr = Wh + (h * 64 + d) * 64;
  float ws = 0.f;
#pragma unroll
  for (int k = 0; k < 64; k += 4) {
    float4 wv4 = *(const float4*)(wr + k);
    ws += (wv4.x + wv4.y) + (wv4.z + wv4.w);
  }
  const float C2 = 2.885390081777927f;   // 2*log2(e)
  const float wsC2 = ws * C2;
  const float Kw = 2.0f * wsC2;
  const size_t base = (size_t)bh * (SK_ * DK_) + d;
  const float* r = Rp + base;
  u16* o = Hst + base;
  int* pg = ctrl + C_PROG + bh * 16;
  float cur[RB_], nxt[RB_];
#pragma unroll
  for (int j = 0; j < RB_; j++) cur[j] = r[(size_t)j * DK_];
  float e = fexp2(cur[0] * C2);          // e_0 (h_{-1} = 0)
  for (int t0 = 0; t0 < SK_; t0 += RB_) {
    const int t1 = t0 + RB_;
    const int tn = (t1 < SK_) ? t1 : t0;  // dummy reload at end
#pragma unroll
    for (int j = 0; j < RB_; j++) nxt[j] = r[(size_t)(tn + j) * DK_];
#pragma unroll
    for (int j = 0; j < RB_; j++) {
      const float a = e + 1.0f;                          // chain 1
      const float bb = __builtin_amdgcn_rcpf(a);         // chain 2
      const float hs = __builtin_fmaf(-2.0f, bb, 1.0f);  // off-chain output
      o[(size_t)(t0 + j) * DK_] = f2h(hs);
      const float rn = (j + 1 < RB_) ? cur[j + 1] : nxt[0];
      const float K = __builtin_fmaf(C2, rn, wsC2);      // off-chain
      const float x = __builtin_fmaf(-Kw, bb, K);        // chain 3
      e = fexp2(x);                                      // chain 4
    }
    if (((t1 & 127) == 0) && (tid & 63) == 0)
      __hip_atomic_store(pg, t1, __ATOMIC_RELEASE, __HIP_MEMORY_SCOPE_AGENT);
#pragma unroll
    for (int j = 0; j < RB_; j++) cur[j] = nxt[j];
  }
  __builtin_amdgcn_s_setprio(0);
}

#define FXM_ 12.0f
__device__ void flash_task(int fidx, const u16* __restrict__ Qb,
                           const u16* __restrict__ Hst, const u16* __restrict__ Vt,
                           u16* __restrict__ Og, u16* smem, int* ctrl) {
  const int tid = threadIdx.x;
  const int w = tid >> 6, lane = tid & 63;
  const int quad = lane >> 4, ln = lane & 15;
  const int bh = fidx >> 4, qtile = fidx & 15;
  const int q0 = qtile * 128 + w * 32;
  u16* Kt = smem;                      // [64][72]
  u16* Vts = smem + 64 * 72;           // [64][72]
  u16* Pw = smem + 2 * 64 * 72 + w * (32 * 72);
  const float scale2 = 0.18033688011112042f;  // log2(e)/sqrt(DK)
  const u16* Qg = Qb + (size_t)bh * SQ_ * DK_;
  const u16* Kg = Hst + (size_t)bh * SK_ * DK_;
  const u16* Vg = Vt + (size_t)bh * DK_ * SK_;
  int* pg = ctrl + C_PROG + bh * 16;
  if (tid == 0) spin_ge(pg, 128);      // rows [0,128) of our bh ready
  __syncthreads();
  h8 qf[2][2];
#pragma unroll
  for (int qt = 0; qt < 2; qt++)
#pragma unroll
    for (int c = 0; c < 2; c++)
      qf[qt][c] = *(const h8*)&Qg[(size_t)(q0 + qt * 16 + ln) * DK_ + c * 32 + quad * 8];
  f4 o[4][2] = {};                 // O^T[d=dt*16+quad*4+r][q=qt*16+ln]
  float l[2] = {0.f, 0.f};
  // staging map: 512 chunks of 16B; thread stages c0=tid and c1=tid+256
  const int c0 = tid, c1 = tid + 256;
  const int r0 = c0 >> 3, o0 = (c0 & 7) * 8;
  const int r1 = c1 >> 3, o1 = (c1 & 7) * 8;
  const u16* kg0 = Kg + (size_t)r0 * DK_ + o0;
  const u16* kg1 = Kg + (size_t)r1 * DK_ + o1;
  const u16* vg0 = Vg + (size_t)r0 * SK_ + o0;
  const u16* vg1 = Vg + (size_t)r1 * SK_ + o1;
  u16* kl0 = &Kt[r0 * 72 + o0];
  u16* kl1 = &Kt[r1 * 72 + o1];
  u16* vl0 = &Vts[r0 * 72 + o0];
  u16* vl1 = &Vts[r1 * 72 + o1];
  // prologue: tile kt=0 (rows [0,128) released above)
  int4 ks0 = *(const int4*)(kg0);
  int4 ks1 = *(const int4*)(kg1);
  int4 vs0 = *(const int4*)(vg0);
  int4 vs1 = *(const int4*)(vg1);
  int seen = 128;
  for (int kt = 0; kt < SK_; kt += 64) {
    if (tid == 0) {   // gate THIS iteration's prefetch (rows [kt+64,kt+128))
      const int need = (kt + 128 <= SK_) ? kt + 128 : SK_;
      if (seen < need) { spin_ge(pg, need); seen = need; }
    }
    __syncthreads();               // gate + prior tile's fragment reads done
    *(int4*)kl0 = ks0;
    *(int4*)kl1 = ks1;
    *(int4*)vl0 = vs0;
    *(int4*)vl1 = vs1;
    __syncthreads();               // tile staged
    h8 kf[4][2], vf[4][2];
#pragma unroll
    for (int m = 0; m < 4; m++) {
      kf[m][0] = *(const h8*)&Kt[(m * 16 + ln) * 72 + quad * 8];
      kf[m][1] = *(const h8*)&Kt[(m * 16 + ln) * 72 + 32 + quad * 8];
    }
#pragma unroll
    for (int dt = 0; dt < 4; dt++) {
      vf[dt][0] = *(const h8*)&Vts[(dt * 16 + ln) * 72 + quad * 8];
      vf[dt][1] = *(const h8*)&Vts[(dt * 16 + ln) * 72 + 32 + quad * 8];
    }
    const int ktn = (kt + 64 < SK_) ? kt + 64 : 0;
    ks0 = *(const int4*)(kg0 + (size_t)ktn * DK_);
    ks1 = *(const int4*)(kg1 + (size_t)ktn * DK_);
    vs0 = *(const int4*)(vg0 + ktn);
    vs1 = *(const int4*)(vg1 + ktn);
    f4 st[4][2];
#pragma unroll
    for (int m = 0; m < 4; m++)
#pragma unroll
      for (int qt = 0; qt < 2; qt++) {
        f4 t = {0.f, 0.f, 0.f, 0.f};
        t = __builtin_amdgcn_mfma_f32_16x16x32_f16(kf[m][0], qf[qt][0], t, 0, 0, 0);
        t = __builtin_amdgcn_mfma_f32_16x16x32_f16(kf[m][1], qf[qt][1], t, 0, 0, 0);
        st[m][qt] = t;
      }
#pragma unroll
    for (int qt = 0; qt < 2; qt++)
#pragma unroll
      for (int m = 0; m < 4; m++) {
        const float p0 = fexp2(__builtin_fmaf(st[m][qt][0], scale2, -FXM_));
        const float p1 = fexp2(__builtin_fmaf(st[m][qt][1], scale2, -FXM_));
        const float p2 = fexp2(__builtin_fmaf(st[m][qt][2], scale2, -FXM_));
        const float p3 = fexp2(__builtin_fmaf(st[m][qt][3], scale2, -FXM_));
        l[qt] += (p0 + p1) + (p2 + p3);
        uint2 pk;
        pk.x = pkrtz(p0, p1);
        pk.y = pkrtz(p2, p3);
        *(uint2*)&Pw[(qt * 16 + ln) * 72 + m * 16 + quad * 4] = pk;
      }
    asm volatile("" ::: "memory");   // wave-private LDS write->read ordering
#pragma unroll
    for (int c = 0; c < 2; c++) {
      h8 pb0 = *(const h8*)&Pw[(0 + ln) * 72 + c * 32 + quad * 8];
      h8 pb1 = *(const h8*)&Pw[(16 + ln) * 72 + c * 32 + quad * 8];
#pragma unroll
      for (int dt = 0; dt < 4; dt++) {
        o[dt][0] = __builtin_amdgcn_mfma_f32_16x16x32_f16(vf[dt][c], pb0, o[dt][0], 0, 0, 0);
        o[dt][1] = __builtin_amdgcn_mfma_f32_16x16x32_f16(vf[dt][c], pb1, o[dt][1], 0, 0, 0);
      }
    }
  }
  const int b = bh >> 4, h = bh & 15;
#pragma unroll
  for (int qt = 0; qt < 2; qt++) {
    float lq = l[qt];
    lq += __shfl_xor(lq, 16);
    lq += __shfl_xor(lq, 32);
    const float linv = __builtin_amdgcn_rcpf(lq);
    const int q = q0 + qt * 16 + ln;
#pragma unroll
    for (int dt = 0; dt < 4; dt++) {
      uint2 pk;
      pk.x = pkrtz(o[dt][qt][0] * linv, o[dt][qt][1] * linv);
      pk.y = pkrtz(o[dt][qt][2] * linv, o[dt][qt][3] * linv);
      *(uint2*)&Og[((size_t)b * SQ_ + q) * D_ + h * DK_ + dt * 16 + quad * 4] = pk;
    }
  }
}

__global__ __launch_bounds__(256, 2)
void rma_recur_flash(const float* __restrict__ Rp, const float* __restrict__ Wh,
                     u16* __restrict__ Hst, const u16* __restrict__ Qb,
                     const u16* __restrict__ Vt, u16* __restrict__ Og,
                     int* __restrict__ ctrl) {
  __shared__ __align__(16) u16 smem[18432];   // flash K/V/P tiles (36.9KB)
  if (blockIdx.x < 8) {
    recur_run(Rp, Wh, Hst, ctrl);
    return;
  }
  flash_task(blockIdx.x - 8, Qb, Hst, Vt, Og, smem, ctrl);
}

// K4: final projection
__global__ __launch_bounds__(256, 2)
void rma_final_gemm(const u16* __restrict__ Og, const u16* __restrict__ Wo,
                    const float* __restrict__ bo, float* __restrict__ out) {
  __shared__ u16 As[64 * 32];
  __shared__ u16 Bs[128 * 32];
  const int m0 = blockIdx.x * 64, n0 = blockIdx.y * 128;
  f4 acc[2][4] = {};
  gemm_mainloop64(Og, Wo, D_, As, Bs, m0, n0, acc);
  const int tid = threadIdx.x;
  const int w = tid >> 6, lane = tid & 63;
  const int quad = lane >> 4, ln = lane & 15;
  const int wm = (w >> 1) * 32, wn = (w & 1) * 64;
#pragma unroll
  for (int i = 0; i < 2; i++)
#pragma unroll
    for (int j = 0; j < 4; j++) {
      const int colg = n0 + wn + j * 16 + ln;
      const float bb = bo[colg];
#pragma unroll
      for (int r = 0; r < 4; r++) {
        const int rowg = m0 + wm + i * 16 + quad * 4 + r;
        out[(size_t)rowg * D_ + colg] = acc[i][j][r] + bb;
      }
    }
}

// ---------------------------------------------------------------- launch
extern "C" void kernel_launch(void* const* d_in, const int* in_sizes, int n_in,
                              void* d_out, int out_size, void* d_ws, size_t ws_size,
                              hipStream_t stream) {
  const float* query = (const float*)d_in[0];
  // d_in[1] = key : unused by the reference forward
  const float* value = (const float*)d_in[2];
  const float* R = (const float*)d_in[3];
  const float* Wq = (const float*)d_in[4];
  const float* bq = (const float*)d_in[5];
  const float* Wv = (const float*)d_in[6];
  const float* bv = (const float*)d_in[7];
  const float* Wr = (const float*)d_in[8];
  const float* br = (const float*)d_in[9];
  const float* W_h = (const float*)d_in[10];
  const float* Wo = (const float*)d_in[11];
  const float* bo = (const float*)d_in[12];
  float* out = (float*)d_out;

  char* ws = (char*)d_ws;
  const size_t MB = 1 << 20;
  u16* Xq = (u16*)(ws + 0 * MB);      // 8MB fp16 query
  u16* Xv = (u16*)(ws + 8 * MB);      // 8MB fp16 value
  u16* Xr = (u16*)(ws + 16 * MB);     // 8MB fp16 R
  u16* Wqb = (u16*)(ws + 24 * MB);    // 2MB
  u16* Wvb = (u16*)(ws + 26 * MB);    // 2MB
  u16* Wrb = (u16*)(ws + 28 * MB);    // 2MB
  u16* Wob = (u16*)(ws + 30 * MB);    // 2MB
  u16* Qb = (u16*)(ws + 32 * MB);     // 8MB fp16 (B,H,SQ,DK)
  u16* Vt = (u16*)(ws + 40 * MB);     // 8MB fp16 (B,H,DK,SK)
  float* Rp = (float*)(ws + 48 * MB); // 16MB f32 (B,H,SK,DK)
  u16* Hs = (u16*)(ws + 64 * MB);     // 8MB fp16 (B,H,SK,DK)
  u16* Og = (u16*)(ws + 72 * MB);     // 8MB fp16 (B,SQ,D)
  int* ctrl = (int*)(ws + 80 * MB);   // 32 spread progress counters

  rma_cast_all<<<dim3(8192), 256, 0, stream>>>(query, value, R, Wq, Wv, Wr, Wo,
                                               Xq, Xv, Xr, Wqb, Wvb, Wrb, Wob, ctrl);
  rma_proj_gemm<<<dim3(32, 8, 3), 256, 0, stream>>>(Xq, Xv, Xr, Wqb, Wvb, Wrb,
                                                    bq, bv, br, Qb, Vt, Rp);
  rma_recur_flash<<<dim3(520), 256, 0, stream>>>(Rp, W_h, Hs, Qb, Vt, Og, ctrl);
  rma_final_gemm<<<dim3(64, 8), 256, 0, stream>>>(Og, Wob, bo, out);
}